// Round 3
// baseline (1189.644 us; speedup 1.0000x reference)
//
#include <hip/hip_runtime.h>
#include <hip/hip_bf16.h>

// GCN 2-layer: h = relu(Agg(x@W1)+b1); out = log_softmax(Agg(h@W2)+b2)
// Agg = D^-1/2 (A+I) D^-1/2.
// v3: bucketized aggregation. Edges bucketed by dst>>7 (782 buckets x 128
// nodes, fixed-cap regions). Aggregation accumulates into LDS acc[128xF]
// per bucket (ds_add_f32, lane=feature -> conflict-free). GEMM epilogues
// pre-scale rows by dinv[row], so messages are just xl'[src] (no per-edge
// dinv gather) and the self-loop term is xl'[g].

#define N_NODES 100000
#define BSH 7
#define BROW 128
#define NB ((N_NODES + BROW - 1) / BROW)   // 782
#define CAP 4096                            // max edges/bucket (uniform E/NB~2046)

// ---- bucketize edges by dst; block-local LDS histogram + range reserve ----
__global__ __launch_bounds__(256) void k_bfill(const int* __restrict__ src,
                                               const int* __restrict__ dst, int E,
                                               int* __restrict__ gfill,
                                               int* __restrict__ bk) {
    __shared__ int cnt[NB];
    __shared__ int off[NB];
    __shared__ int cur[NB];
    int t = threadIdx.x;
    int chunk = (E + gridDim.x - 1) / gridDim.x;
    int e0 = blockIdx.x * chunk;
    int e1 = min(E, e0 + chunk);
    for (int b = t; b < NB; b += 256) { cnt[b] = 0; cur[b] = 0; }
    __syncthreads();
    for (int e = e0 + t; e < e1; e += 256)
        atomicAdd(&cnt[dst[e] >> BSH], 1);
    __syncthreads();
    for (int b = t; b < NB; b += 256)
        off[b] = cnt[b] ? atomicAdd(&gfill[b], cnt[b]) : 0;
    __syncthreads();
    for (int e = e0 + t; e < e1; e += 256) {
        int d = dst[e];
        int b = d >> BSH;
        int p = off[b] + atomicAdd(&cur[b], 1);
        if (p < CAP)
            bk[(size_t)b * CAP + p] = ((d & (BROW - 1)) << 17) | src[e];
    }
}

// ---- per-bucket degree histogram -> dinv ----
__global__ __launch_bounds__(256) void k_bdeg(const int* __restrict__ gfill,
                                              const int* __restrict__ bk,
                                              float* __restrict__ dinv, int n) {
    __shared__ int deg[BROW];
    int t = threadIdx.x;
    int b = blockIdx.x;
    if (t < BROW) deg[t] = 0;
    __syncthreads();
    int bn = min(gfill[b], CAP);
    const int* bp = bk + (size_t)b * CAP;
    for (int i = t; i < bn; i += 256)
        atomicAdd(&deg[bp[i] >> 17], 1);
    __syncthreads();
    if (t < BROW) {
        int g = b * BROW + t;
        if (g < n) dinv[g] = rsqrtf((float)(deg[t] + 1));
    }
}

// ---------------- GEMM1: [n,256] @ [256,64], row-scaled by dinv ----------------
// 8x8 register tile; W1 (64KB) + transposed x tile (16KB) in LDS; x-fragment
// reads vectorized (2 x b128 per k).

__global__ __launch_bounds__(256, 2) void k_gemm1(const float* __restrict__ x,
                                                  const float* __restrict__ W,
                                                  const float* __restrict__ dinv,
                                                  float* __restrict__ out, int n) {
    __shared__ float Wl[256 * 64];    // [k][j]
    __shared__ float xtT[16 * 256];   // [k][row]

    int t = threadIdx.x;
    int cg = t & 7;
    int rg = t >> 3;
    int rowBase = blockIdx.x * 256;

    {
        const float4* W4 = reinterpret_cast<const float4*>(W);
        float4* Wl4 = reinterpret_cast<float4*>(Wl);
#pragma unroll
        for (int i = 0; i < 16; ++i)
            Wl4[t + i * 256] = W4[t + i * 256];
    }

    float acc[8][8];
#pragma unroll
    for (int i = 0; i < 8; ++i)
#pragma unroll
        for (int j = 0; j < 8; ++j) acc[i][j] = 0.f;

    for (int kc = 0; kc < 256; kc += 16) {
        __syncthreads();
#pragma unroll
        for (int it = 0; it < 4; ++it) {
            int f4 = t + it * 256;
            int r  = f4 >> 2;
            int c4 = f4 & 3;
            float4 v = make_float4(0.f, 0.f, 0.f, 0.f);
            int gr = rowBase + r;
            if (gr < n)
                v = *reinterpret_cast<const float4*>(&x[(size_t)gr * 256 + kc + c4 * 4]);
            xtT[(c4 * 4 + 0) * 256 + r] = v.x;
            xtT[(c4 * 4 + 1) * 256 + r] = v.y;
            xtT[(c4 * 4 + 2) * 256 + r] = v.z;
            xtT[(c4 * 4 + 3) * 256 + r] = v.w;
        }
        __syncthreads();
#pragma unroll
        for (int k = 0; k < 16; ++k) {
            float4 xa = *reinterpret_cast<const float4*>(&xtT[k * 256 + rg * 8]);
            float4 xb = *reinterpret_cast<const float4*>(&xtT[k * 256 + rg * 8 + 4]);
            float xv[8] = {xa.x, xa.y, xa.z, xa.w, xb.x, xb.y, xb.z, xb.w};
            float4 w0 = *reinterpret_cast<const float4*>(&Wl[(kc + k) * 64 + cg * 8]);
            float4 w1 = *reinterpret_cast<const float4*>(&Wl[(kc + k) * 64 + cg * 8 + 4]);
            float wv[8] = {w0.x, w0.y, w0.z, w0.w, w1.x, w1.y, w1.z, w1.w};
#pragma unroll
            for (int i = 0; i < 8; ++i)
#pragma unroll
                for (int j = 0; j < 8; ++j)
                    acc[i][j] = fmaf(xv[i], wv[j], acc[i][j]);
        }
    }

#pragma unroll
    for (int i = 0; i < 8; ++i) {
        int row = rowBase + rg * 8 + i;
        if (row < n) {
            float di = dinv[row];
            float* op = &out[(size_t)row * 64 + cg * 8];
            float4 v0 = {acc[i][0] * di, acc[i][1] * di, acc[i][2] * di, acc[i][3] * di};
            float4 v1 = {acc[i][4] * di, acc[i][5] * di, acc[i][6] * di, acc[i][7] * di};
            *reinterpret_cast<float4*>(op) = v0;
            *reinterpret_cast<float4*>(op + 4) = v1;
        }
    }
}

// ---- Aggregation L1: per-bucket LDS accumulate (64-wide) + bias + relu ----
__global__ __launch_bounds__(256) void k_agg1(const float* __restrict__ xl,
                                              const int* __restrict__ gfill,
                                              const int* __restrict__ bk,
                                              const float* __restrict__ dinv,
                                              const float* __restrict__ b1,
                                              float* __restrict__ h, int n) {
    __shared__ float acc[BROW * 64];   // 32 KB
    int t = threadIdx.x;
    int b = blockIdx.x;
    for (int i = t; i < BROW * 64; i += 256) acc[i] = 0.f;
    __syncthreads();
    int bn = min(gfill[b], CAP);
    const int* bp = bk + (size_t)b * CAP;
    int w = t >> 6, lane = t & 63;
    for (int i0 = w * 64; i0 < bn; i0 += 256) {
        int m = min(64, bn - i0);
        int ev = (lane < m) ? bp[i0 + lane] : 0;
#pragma unroll 4
        for (int j = 0; j < m; ++j) {
            int e = __shfl(ev, j);
            int s = e & 0x1FFFF;
            int dl = e >> 17;
            atomicAdd(&acc[dl * 64 + lane], xl[(size_t)s * 64 + lane]);
        }
    }
    __syncthreads();
    for (int i = w; i < BROW; i += 4) {
        int g = b * BROW + i;
        if (g < n) {
            float tot = acc[i * 64 + lane] + xl[(size_t)g * 64 + lane];
            float o = fmaf(tot, dinv[g], b1[lane]);
            h[(size_t)g * 64 + lane] = fmaxf(o, 0.f);
        }
    }
}

// ---------------- GEMM2: [n,64] @ [64,16], row-scaled by dinv ----------------
__global__ __launch_bounds__(256) void k_gemm2(const float* __restrict__ h,
                                               const float* __restrict__ W,
                                               const float* __restrict__ dinv,
                                               float* __restrict__ out, int n) {
    int row = blockIdx.x * 256 + threadIdx.x;
    if (row >= n) return;
    float acc[16];
#pragma unroll
    for (int j = 0; j < 16; ++j) acc[j] = 0.f;
    const float* hr = &h[(size_t)row * 64];
#pragma unroll
    for (int k4 = 0; k4 < 16; ++k4) {
        float4 hv = *reinterpret_cast<const float4*>(&hr[k4 * 4]);
        float hvv[4] = {hv.x, hv.y, hv.z, hv.w};
#pragma unroll
        for (int kk = 0; kk < 4; ++kk) {
            const float* wr = &W[(size_t)(k4 * 4 + kk) * 16];
#pragma unroll
            for (int j = 0; j < 16; ++j) acc[j] = fmaf(hvv[kk], wr[j], acc[j]);
        }
    }
    float di = dinv[row];
    float* op = &out[(size_t)row * 16];
#pragma unroll
    for (int j = 0; j < 16; j += 4) {
        float4 v = {acc[j] * di, acc[j + 1] * di, acc[j + 2] * di, acc[j + 3] * di};
        *reinterpret_cast<float4*>(&op[j]) = v;
    }
}

// ---- Aggregation L2: per-bucket LDS accumulate (16-wide) + bias + log_softmax ----
__global__ __launch_bounds__(256) void k_agg2(const float* __restrict__ xl,
                                              const int* __restrict__ gfill,
                                              const int* __restrict__ bk,
                                              const float* __restrict__ dinv,
                                              const float* __restrict__ b2,
                                              float* __restrict__ out, int n) {
    __shared__ float acc[BROW * 16];   // 8 KB
    int t = threadIdx.x;
    int b = blockIdx.x;
    for (int i = t; i < BROW * 16; i += 256) acc[i] = 0.f;
    __syncthreads();
    int bn = min(gfill[b], CAP);
    const int* bp = bk + (size_t)b * CAP;
    int w = t >> 6, lane = t & 63;
    int grp = lane >> 4, l = lane & 15;
    for (int i0 = w * 64; i0 < bn; i0 += 256) {
        int m = min(64, bn - i0);
        int ev = (lane < m) ? bp[i0 + lane] : 0;
        for (int j4 = 0; j4 < m; j4 += 4) {
            int idx = j4 + grp;
            int e = __shfl(ev, idx);
            if (idx < m) {
                int s = e & 0x1FFFF;
                int dl = e >> 17;
                atomicAdd(&acc[dl * 16 + l], xl[(size_t)s * 16 + l]);
            }
        }
    }
    __syncthreads();
    for (int i = t >> 4; i < BROW; i += 16) {
        int g = b * BROW + i;
        if (g < n) {
            float v = fmaf(acc[i * 16 + l] + xl[(size_t)g * 16 + l], dinv[g], b2[l]);
            float mx = v;
#pragma unroll
            for (int o = 1; o < 16; o <<= 1) mx = fmaxf(mx, __shfl_xor(mx, o, 16));
            float ex = expf(v - mx);
            float ss = ex;
#pragma unroll
            for (int o = 1; o < 16; o <<= 1) ss += __shfl_xor(ss, o, 16);
            out[(size_t)g * 16 + l] = v - mx - logf(ss);
        }
    }
}

// ---------------- launch ----------------

extern "C" void kernel_launch(void* const* d_in, const int* in_sizes, int n_in,
                              void* d_out, int out_size, void* d_ws, size_t ws_size,
                              hipStream_t stream) {
    const float* x  = (const float*)d_in[0];
    const int*   ei = (const int*)d_in[1];
    const float* W1 = (const float*)d_in[2];
    const float* b1 = (const float*)d_in[3];
    const float* W2 = (const float*)d_in[4];
    const float* b2 = (const float*)d_in[5];
    float* outp = (float*)d_out;

    const int n = N_NODES;
    const int E = in_sizes[1] / 2;
    const int* src = ei;
    const int* dst = ei + E;

    size_t off = 0;
    char* base = (char*)d_ws;
    auto take = [&](size_t bytes) { size_t r = off; off += (bytes + 255) & ~(size_t)255; return r; };
    int*   gfill = (int*)(base + take((size_t)NB * 4));             // zeroed below
    int*   bk    = (int*)(base + take((size_t)NB * CAP * 4));       // 12.8 MB
    float* dinv  = (float*)(base + take((size_t)n * 4));
    float* xl1   = (float*)(base + take((size_t)n * 64 * 4));
    float* hbuf  = (float*)(base + take((size_t)n * 64 * 4));
    float* xl2   = (float*)(base + take((size_t)n * 16 * 4));

    hipMemsetAsync(gfill, 0, (size_t)NB * 4, stream);

    k_bfill<<<256, 256, 0, stream>>>(src, dst, E, gfill, bk);
    k_bdeg<<<NB, 256, 0, stream>>>(gfill, bk, dinv, n);
    k_gemm1<<<(n + 255) / 256, 256, 0, stream>>>(x, W1, dinv, xl1, n);
    k_agg1<<<NB, 256, 0, stream>>>(xl1, gfill, bk, dinv, b1, hbuf, n);
    k_gemm2<<<(n + 255) / 256, 256, 0, stream>>>(hbuf, W2, dinv, xl2, n);
    k_agg2<<<NB, 256, 0, stream>>>(xl2, gfill, bk, dinv, b2, outp, n);
}

// Round 4
// 386.232 us; speedup vs baseline: 3.0801x; 3.0801x over previous
//
#include <hip/hip_runtime.h>
#include <hip/hip_bf16.h>

// GCN 2-layer: h = relu(Agg(x@W1)+b1); out = log_softmax(Agg(h@W2)+b2)
// Agg = D^-1/2 (A+I) D^-1/2.
// v4: CSR build via dst-buckets (bfill -> scan -> bcsr counting-sort; dense
// coalesced csrc writes), aggregation node-parallel (one wave / wave-slice
// per node). GEMM epilogues pre-scale rows by dinv[row] so agg needs no
// per-edge dinv gather: out = (sum xl'[src] + xl'[g]) * dinv[g] + b.

#define N_NODES 100000
#define BSH 7
#define BROW 128
#define NB ((N_NODES + BROW - 1) / BROW)   // 782
#define CAP 4096                            // max edges/bucket (uniform E/NB ~2046)

// ---- bucketize edges by dst; block-local LDS histogram + range reserve ----
__global__ __launch_bounds__(256) void k_bfill(const int* __restrict__ src,
                                               const int* __restrict__ dst, int E,
                                               int* __restrict__ gfill,
                                               int* __restrict__ bk) {
    __shared__ int cnt[NB];
    __shared__ int off[NB];
    __shared__ int cur[NB];
    int t = threadIdx.x;
    int chunk = (E + gridDim.x - 1) / gridDim.x;
    int e0 = blockIdx.x * chunk;
    int e1 = min(E, e0 + chunk);
    for (int b = t; b < NB; b += 256) { cnt[b] = 0; cur[b] = 0; }
    __syncthreads();
    for (int e = e0 + t; e < e1; e += 256)
        atomicAdd(&cnt[dst[e] >> BSH], 1);
    __syncthreads();
    for (int b = t; b < NB; b += 256)
        off[b] = cnt[b] ? atomicAdd(&gfill[b], cnt[b]) : 0;
    __syncthreads();
    for (int e = e0 + t; e < e1; e += 256) {
        int d = dst[e];
        int b = d >> BSH;
        int p = off[b] + atomicAdd(&cur[b], 1);
        if (p < CAP)
            bk[(size_t)b * CAP + p] = ((d & (BROW - 1)) << 17) | src[e];
    }
}

// ---- exclusive scan of gfill[NB] -> bbase ----
__global__ __launch_bounds__(1024) void k_scanN(const int* __restrict__ gfill,
                                                int* __restrict__ bbase) {
    __shared__ int s[1024];
    int t = threadIdx.x;
    int v = (t < NB) ? gfill[t] : 0;
    s[t] = v;
    __syncthreads();
    for (int off = 1; off < 1024; off <<= 1) {
        int a = (t >= off) ? s[t - off] : 0;
        __syncthreads();
        s[t] += a;
        __syncthreads();
    }
    if (t < NB) bbase[t] = s[t] - v;
}

// ---- per-bucket: degree histogram -> dinv + rowptr; counting-sort -> csrc ----
__global__ __launch_bounds__(256) void k_bcsr(const int* __restrict__ gfill,
                                              const int* __restrict__ bbase,
                                              const int* __restrict__ bk,
                                              float* __restrict__ dinv,
                                              int* __restrict__ rowptr,
                                              int* __restrict__ csrc) {
    __shared__ int deg[BROW];
    __shared__ int pos[BROW];
    __shared__ int cur[BROW];
    int t = threadIdx.x;
    int b = blockIdx.x;
    if (t < BROW) deg[t] = 0;
    __syncthreads();
    int bn = min(gfill[b], CAP);
    const int* bp = bk + (size_t)b * CAP;
    for (int i = t; i < bn; i += 256)
        atomicAdd(&deg[bp[i] >> 17], 1);
    __syncthreads();
    if (t < BROW) pos[t] = deg[t];
    __syncthreads();
    for (int off = 1; off < BROW; off <<= 1) {
        int a = (t >= off && t < BROW) ? pos[t - off] : 0;
        __syncthreads();
        if (t < BROW) pos[t] += a;
        __syncthreads();
    }
    if (t < BROW) {
        int g = (b << BSH) + t;
        int gp = bbase[b] + pos[t] - deg[t];   // exclusive
        if (g <= N_NODES) rowptr[g] = gp;      // g==N_NODES happens once (last bucket) -> rowptr[n]=E
        if (g < N_NODES) dinv[g] = rsqrtf((float)(deg[t] + 1));
        cur[t] = gp;
    }
    __syncthreads();
    for (int i = t; i < bn; i += 256) {
        int e = bp[i];
        int p = atomicAdd(&cur[e >> 17], 1);
        csrc[p] = e & 0x1FFFF;
    }
}

// ---------------- GEMM1: [n,256] @ [256,64], rows scaled by dinv ----------------
// 8x8 register tile. Per 16-k chunk: x tile transposed into LDS (stride 260,
// 2-way-free banks, b128-aligned) + W chunk (16x64 = 4KB). LDS ~21KB ->
// 4 blocks/CU (VGPR-capped), LDS-unit is the floor (~31us ideal).

__global__ __launch_bounds__(256, 4) void k_gemm1(const float* __restrict__ x,
                                                  const float* __restrict__ W,
                                                  const float* __restrict__ dinv,
                                                  float* __restrict__ out, int n) {
    __shared__ float xtT[16 * 260];   // [k][row], padded stride
    __shared__ float Wc[16 * 64];     // [k][j]

    int t = threadIdx.x;
    int cg = t & 7;
    int rg = t >> 3;
    int rowBase = blockIdx.x * 256;

    float acc[8][8];
#pragma unroll
    for (int i = 0; i < 8; ++i)
#pragma unroll
        for (int j = 0; j < 8; ++j) acc[i][j] = 0.f;

    for (int kc = 0; kc < 256; kc += 16) {
        __syncthreads();
        // stage x chunk transposed
#pragma unroll
        for (int it = 0; it < 4; ++it) {
            int f4 = t + it * 256;
            int r  = f4 >> 2;
            int c4 = f4 & 3;
            float4 v = make_float4(0.f, 0.f, 0.f, 0.f);
            int gr = rowBase + r;
            if (gr < n)
                v = *reinterpret_cast<const float4*>(&x[(size_t)gr * 256 + kc + c4 * 4]);
            xtT[(c4 * 4 + 0) * 260 + r] = v.x;
            xtT[(c4 * 4 + 1) * 260 + r] = v.y;
            xtT[(c4 * 4 + 2) * 260 + r] = v.z;
            xtT[(c4 * 4 + 3) * 260 + r] = v.w;
        }
        // stage W chunk: rows kc..kc+15 = 256 float4
        reinterpret_cast<float4*>(Wc)[t] = reinterpret_cast<const float4*>(W)[kc * 16 + t];
        __syncthreads();
#pragma unroll
        for (int k = 0; k < 16; ++k) {
            float4 xa = *reinterpret_cast<const float4*>(&xtT[k * 260 + rg * 8]);
            float4 xb = *reinterpret_cast<const float4*>(&xtT[k * 260 + rg * 8 + 4]);
            float xv[8] = {xa.x, xa.y, xa.z, xa.w, xb.x, xb.y, xb.z, xb.w};
            float4 w0 = *reinterpret_cast<const float4*>(&Wc[k * 64 + cg * 8]);
            float4 w1 = *reinterpret_cast<const float4*>(&Wc[k * 64 + cg * 8 + 4]);
            float wv[8] = {w0.x, w0.y, w0.z, w0.w, w1.x, w1.y, w1.z, w1.w};
#pragma unroll
            for (int i = 0; i < 8; ++i)
#pragma unroll
                for (int j = 0; j < 8; ++j)
                    acc[i][j] = fmaf(xv[i], wv[j], acc[i][j]);
        }
    }

#pragma unroll
    for (int i = 0; i < 8; ++i) {
        int row = rowBase + rg * 8 + i;
        if (row < n) {
            float di = dinv[row];
            float* op = &out[(size_t)row * 64 + cg * 8];
            float4 v0 = {acc[i][0] * di, acc[i][1] * di, acc[i][2] * di, acc[i][3] * di};
            float4 v1 = {acc[i][4] * di, acc[i][5] * di, acc[i][6] * di, acc[i][7] * di};
            *reinterpret_cast<float4*>(op) = v0;
            *reinterpret_cast<float4*>(op + 4) = v1;
        }
    }
}

// ---- Aggregation L1 (64-wide): node-per-wave CSR gather + bias + relu ----
__global__ __launch_bounds__(256) void k_agg1(const float* __restrict__ xl,
                                              const int* __restrict__ rowptr,
                                              const int* __restrict__ csrc,
                                              const float* __restrict__ dinv,
                                              const float* __restrict__ b1,
                                              float* __restrict__ h, int n) {
    int t = threadIdx.x;
    int lane = t & 63;
    int node = blockIdx.x * 4 + (t >> 6);
    if (node >= n) return;
    float acc = xl[(size_t)node * 64 + lane];      // self-loop (pre-scaled)
    int p = rowptr[node], p1 = rowptr[node + 1];
    for (; p + 3 < p1; p += 4) {
        int s0 = csrc[p], s1 = csrc[p + 1], s2 = csrc[p + 2], s3 = csrc[p + 3];
        float v0 = xl[(size_t)s0 * 64 + lane];
        float v1 = xl[(size_t)s1 * 64 + lane];
        float v2 = xl[(size_t)s2 * 64 + lane];
        float v3 = xl[(size_t)s3 * 64 + lane];
        acc += v0; acc += v1; acc += v2; acc += v3;
    }
    for (; p < p1; ++p)
        acc += xl[(size_t)csrc[p] * 64 + lane];
    float o = fmaf(acc, dinv[node], b1[lane]);
    h[(size_t)node * 64 + lane] = fmaxf(o, 0.f);
}

// ---------------- GEMM2: [n,64] @ [64,16], rows scaled by dinv ----------------
__global__ __launch_bounds__(256) void k_gemm2(const float* __restrict__ h,
                                               const float* __restrict__ W,
                                               const float* __restrict__ dinv,
                                               float* __restrict__ out, int n) {
    int row = blockIdx.x * 256 + threadIdx.x;
    if (row >= n) return;
    float acc[16];
#pragma unroll
    for (int j = 0; j < 16; ++j) acc[j] = 0.f;
    const float* hr = &h[(size_t)row * 64];
#pragma unroll
    for (int k4 = 0; k4 < 16; ++k4) {
        float4 hv = *reinterpret_cast<const float4*>(&hr[k4 * 4]);
        float hvv[4] = {hv.x, hv.y, hv.z, hv.w};
#pragma unroll
        for (int kk = 0; kk < 4; ++kk) {
            const float* wr = &W[(size_t)(k4 * 4 + kk) * 16];
#pragma unroll
            for (int j = 0; j < 16; ++j) acc[j] = fmaf(hvv[kk], wr[j], acc[j]);
        }
    }
    float di = dinv[row];
    float* op = &out[(size_t)row * 16];
#pragma unroll
    for (int j = 0; j < 16; j += 4) {
        float4 v = {acc[j] * di, acc[j + 1] * di, acc[j + 2] * di, acc[j + 3] * di};
        *reinterpret_cast<float4*>(&op[j]) = v;
    }
}

// ---- Aggregation L2 (16-wide): 16 lanes/node CSR gather + bias + log_softmax ----
__global__ __launch_bounds__(256) void k_agg2(const float* __restrict__ xl,
                                              const int* __restrict__ rowptr,
                                              const int* __restrict__ csrc,
                                              const float* __restrict__ dinv,
                                              const float* __restrict__ b2,
                                              float* __restrict__ out, int n) {
    int t = threadIdx.x;
    int l = t & 15;
    int node = blockIdx.x * 16 + (t >> 4);
    if (node >= n) return;
    float acc = xl[(size_t)node * 16 + l];
    int p = rowptr[node], p1 = rowptr[node + 1];
    for (; p + 1 < p1; p += 2) {
        int s0 = csrc[p], s1 = csrc[p + 1];
        float v0 = xl[(size_t)s0 * 16 + l];
        float v1 = xl[(size_t)s1 * 16 + l];
        acc += v0; acc += v1;
    }
    if (p < p1)
        acc += xl[(size_t)csrc[p] * 16 + l];
    float v = fmaf(acc, dinv[node], b2[l]);
    float mx = v;
#pragma unroll
    for (int o = 1; o < 16; o <<= 1) mx = fmaxf(mx, __shfl_xor(mx, o, 16));
    float ex = expf(v - mx);
    float ss = ex;
#pragma unroll
    for (int o = 1; o < 16; o <<= 1) ss += __shfl_xor(ss, o, 16);
    out[(size_t)node * 16 + l] = v - mx - logf(ss);
}

// ---------------- launch ----------------

extern "C" void kernel_launch(void* const* d_in, const int* in_sizes, int n_in,
                              void* d_out, int out_size, void* d_ws, size_t ws_size,
                              hipStream_t stream) {
    const float* x  = (const float*)d_in[0];
    const int*   ei = (const int*)d_in[1];
    const float* W1 = (const float*)d_in[2];
    const float* b1 = (const float*)d_in[3];
    const float* W2 = (const float*)d_in[4];
    const float* b2 = (const float*)d_in[5];
    float* outp = (float*)d_out;

    const int n = N_NODES;
    const int E = in_sizes[1] / 2;
    const int* src = ei;
    const int* dst = ei + E;

    size_t off = 0;
    char* base = (char*)d_ws;
    auto take = [&](size_t bytes) { size_t r = off; off += (bytes + 255) & ~(size_t)255; return r; };
    int*   gfill  = (int*)(base + take((size_t)NB * 4));            // zeroed below
    int*   bbase  = (int*)(base + take((size_t)NB * 4));
    int*   bk     = (int*)(base + take((size_t)NB * CAP * 4));      // 12.8 MB
    float* dinv   = (float*)(base + take((size_t)n * 4));
    int*   rowptr = (int*)(base + take((size_t)(n + 1) * 4));
    int*   csrc   = (int*)(base + take((size_t)E * 4));
    float* xl1    = (float*)(base + take((size_t)n * 64 * 4));
    float* hbuf   = (float*)(base + take((size_t)n * 64 * 4));
    float* xl2    = (float*)(base + take((size_t)n * 16 * 4));

    hipMemsetAsync(gfill, 0, (size_t)NB * 4, stream);

    k_bfill<<<256, 256, 0, stream>>>(src, dst, E, gfill, bk);
    k_scanN<<<1, 1024, 0, stream>>>(gfill, bbase);
    k_bcsr<<<NB, 256, 0, stream>>>(gfill, bbase, bk, dinv, rowptr, csrc);

    k_gemm1<<<(n + 255) / 256, 256, 0, stream>>>(x, W1, dinv, xl1, n);
    k_agg1<<<(n + 3) / 4, 256, 0, stream>>>(xl1, rowptr, csrc, dinv, b1, hbuf, n);
    k_gemm2<<<(n + 255) / 256, 256, 0, stream>>>(hbuf, W2, dinv, xl2, n);
    k_agg2<<<(n + 15) / 16, 256, 0, stream>>>(xl2, rowptr, csrc, dinv, b2, outp, n);
}